// Round 10
// baseline (33.484 us; speedup 1.0000x reference)
//
#include <hip/hip_runtime.h>

#define TT 4096
#define DD 256
#define BT 64
#define HW 32
#define WIN 128
#define YP 264
#define YFP 257

typedef __attribute__((ext_vector_type(8))) short short8;
typedef __attribute__((ext_vector_type(4))) float f32x4;
typedef __attribute__((ext_vector_type(2))) unsigned int u32x2;

__device__ __forceinline__ unsigned int f2bf(float f) {
    unsigned int u = __builtin_bit_cast(unsigned int, f);
    u += 0x7fffu + ((u >> 16) & 1u);          // RNE
    return u >> 16;
}
__device__ __forceinline__ float bf2f(unsigned int h) {
    unsigned int u = h << 16;
    return __builtin_bit_cast(float, u);
}

#define INV_E 0.36787944117144233f
#define RDEC  0.69220062755534635f            // exp(-1/e)

// ---------------- kPre: W fp32 -> bf16 (once, 128 KB out) ----------------
__global__ __launch_bounds__(256)
void kPre(const float* __restrict__ Win, unsigned short* __restrict__ Wbf) {
    int i = ((int)blockIdx.x * 256 + (int)threadIdx.x) * 4;
    float4 v = *(const float4*)(Win + i);
    u32x2 p;
    p.x = f2bf(v.x) | (f2bf(v.y) << 16);
    p.y = f2bf(v.z) | (f2bf(v.w) << 16);
    *(u32x2*)(Wbf + i) = p;
}

// ---------------- kMain: fused conv-scan + proj GEMM, 1024 threads ----------
__global__ __launch_bounds__(1024)
void kMain(const float* __restrict__ x, const float* __restrict__ mask,
           const unsigned short* __restrict__ Wbf, const float* __restrict__ bin,
           float* __restrict__ out)
{
    __shared__ float          yF[BT][YFP];     // fwd partial F (fp32, 65.8 KB)
    __shared__ unsigned short yB[BT][YP];      // (B-v) then final y bf16 (33.8 KB)
    __shared__ float wv[WIN], rp[WIN];
    __shared__ float cA[DD], cC[DD];           // scan carries (fwd@47, bwd@80)
    __shared__ float sp[16][BT];
    __shared__ float s_l[BT];

    const int tid  = threadIdx.x;
    const int orig = blockIdx.x;
    const int wg   = (orig & 7) * 32 + (orig >> 3);   // XCD-contiguous row tiles
    const int b    = wg >> 6;
    const int r0   = (wg & 63) * BT;
    const int base = r0 - HW;

    if (tid < WIN) {
        rp[tid] = __expf(-(float)tid * INV_E);
        int j = base + tid;
        wv[tid] = (j >= 0 && j < TT) ? __expf(mask[b * TT + j] * INV_E) : 0.0f;
    }
    __syncthreads();

    const int w = tid >> 6, lane = tid & 63;
    const int lr = lane & 15, lg = lane >> 4;
    const int wr = w >> 2, wc = w & 3;

    // ---- phase 1: 4 balanced depth-48 chains (g = tid>>8), column c ----
    // window rows t in [0,128), main rows t in [32,96), output i = t-32.
    {
        const int g = tid >> 8, c = tid & 255;
        const float* xc = x + (size_t)b * TT * DD + c;
        if (g == 0) {                                 // fwd [0,48): store i<16, carry cA@47
            float f = 0.0f;
            #pragma unroll 8
            for (int t = 0; t < 32; ++t) {
                int j = base + t; j = max(j, 0);
                f = fmaf(RDEC, f, xc[(size_t)j * DD] * wv[t]);
            }
            #pragma unroll 8
            for (int t = 32; t < 48; ++t) {
                f = fmaf(RDEC, f, xc[(size_t)(base + t) * DD] * wv[t]);
                yF[t - 32][c] = f;
            }
            cA[c] = f;
        } else if (g == 1) {                          // fwd [48,96): store i in [16,64)
            float f = 0.0f;
            #pragma unroll 8
            for (int t = 48; t < 96; ++t) {
                f = fmaf(RDEC, f, xc[(size_t)(base + t) * DD] * wv[t]);
                yF[t - 32][c] = f;
            }
        } else if (g == 2) {                          // bwd [80,128): store i>=48, carry cC@80
            float bb = 0.0f;
            #pragma unroll 8
            for (int t = 127; t >= 96; --t) {
                int j = base + t; j = min(j, TT - 1);
                bb = fmaf(RDEC, bb, xc[(size_t)j * DD] * wv[t]);
            }
            #pragma unroll 8
            for (int t = 95; t >= 80; --t) {
                float v = xc[(size_t)(base + t) * DD] * wv[t];
                bb = fmaf(RDEC, bb, v);
                yB[t - 32][c] = (unsigned short)f2bf(bb - v);
            }
            cC[c] = bb;
        } else {                                      // bwd [32,80): store i in [0,48)
            float bb = 0.0f;
            #pragma unroll 8
            for (int t = 79; t >= 32; --t) {
                float v = xc[(size_t)(base + t) * DD] * wv[t];
                bb = fmaf(RDEC, bb, v);
                yB[t - 32][c] = (unsigned short)f2bf(bb - v);
            }
        }
    }
    // attn row sums (bias term): 16 groups x 8 window terms
    {
        int row = tid & 63, q = tid >> 6;
        float s = 0.0f;
        #pragma unroll
        for (int tt = 0; tt < 8; ++tt) {
            int t = 8 * q + tt;
            int d = row + HW - t; d = (d < 0) ? -d : d;
            s = fmaf(rp[d], wv[t], s);
        }
        sp[q][row] = s;
    }
    __syncthreads();

    // ---- combine: y = F + (B-v) + [i>=16] rp[i-15]*cA + [i<48] rp[48-i]*cC ----
    #pragma unroll
    for (int e = 0; e < 16; ++e) {
        int idx = (e << 10) | tid;
        int i = idx >> 8, c = idx & 255;
        float yv = yF[i][c] + bf2f(yB[i][c]);
        if (i >= 16) yv += rp[i - 15] * cA[c];
        if (i < 48)  yv += rp[48 - i] * cC[c];
        yB[i][c] = (unsigned short)f2bf(yv);
    }
    if (tid < BT) {
        float s = 0.0f;
        #pragma unroll
        for (int q = 0; q < 16; ++q) s += sp[q][tid];
        s_l[tid] = s;
    }
    __syncthreads();                                  // yB final + s_l ready

    // ---- phase 2: out = y @ W^T; B-frags direct global->reg, no barriers ----
    // wave w: rows [16wr,16wr+16), cols [64wc,64wc+64). W is L2-resident bf16.
    f32x4 acc[4];
    #pragma unroll
    for (int n = 0; n < 4; ++n) acc[n] = (f32x4){0.f, 0.f, 0.f, 0.f};

    const unsigned short* wbase = Wbf + (size_t)(64 * wc + lr) * DD + 8 * lg;
    short8 bcur[4], bnxt[4];
    #pragma unroll
    for (int n = 0; n < 4; ++n)
        bcur[n] = *(const short8*)(wbase + (size_t)(16 * n) * DD);

    #pragma unroll
    for (int ch = 0; ch < 8; ++ch) {
        if (ch < 7) {
            #pragma unroll
            for (int n = 0; n < 4; ++n)
                bnxt[n] = *(const short8*)(wbase + (size_t)(16 * n) * DD + 32 * (ch + 1));
        }
        short8 af = *(const short8*)&yB[16 * wr + lr][32 * ch + 8 * lg];
        #pragma unroll
        for (int n = 0; n < 4; ++n)
            acc[n] = __builtin_amdgcn_mfma_f32_16x16x32_bf16(af, bcur[n], acc[n], 0, 0, 0);
        #pragma unroll
        for (int n = 0; n < 4; ++n) bcur[n] = bnxt[n];
    }

    // ---- epilogue (C/D map: row=(lane>>4)*4+j, col=lane&15; validated) ----
    float bcol[4];
    #pragma unroll
    for (int n = 0; n < 4; ++n) bcol[n] = bin[64 * wc + 16 * n + lr];
    float* ob = out + ((size_t)(b * TT + r0)) * DD;
    #pragma unroll
    for (int n = 0; n < 4; ++n)
        #pragma unroll
        for (int j = 0; j < 4; ++j) {
            int i = 16 * wr + 4 * lg + j;
            ob[(size_t)i * DD + 64 * wc + 16 * n + lr] = acc[n][j] + s_l[i] * bcol[n];
        }
}

extern "C" void kernel_launch(void* const* d_in, const int* in_sizes, int n_in,
                              void* d_out, int out_size, void* d_ws, size_t ws_size,
                              hipStream_t stream) {
    const float* x    = (const float*)d_in[0];
    const float* mask = (const float*)d_in[1];
    const float* Win  = (const float*)d_in[2];
    const float* bin  = (const float*)d_in[3];
    float* out = (float*)d_out;

    const int nb = in_sizes[0] / (TT * DD);           // 4 batches
    unsigned short* Wbf = (unsigned short*)d_ws;      // 128 KB bf16 W

    hipLaunchKernelGGL(kPre, dim3(DD * DD / 1024), dim3(256), 0, stream, Win, Wbf);
    hipLaunchKernelGGL(kMain, dim3(nb * (TT / BT)), dim3(1024), 0, stream,
                       x, mask, Wbf, bin, out);
}

// Round 11
// 23.106 us; speedup vs baseline: 1.4491x; 1.4491x over previous
//
#include <hip/hip_runtime.h>

#define TT 4096
#define DD 256
#define BT 64
#define HW 32
#define WIN 128
#define YP 264
#define YFP 257

typedef __attribute__((ext_vector_type(8))) short short8;
typedef __attribute__((ext_vector_type(4))) float f32x4;
typedef __attribute__((ext_vector_type(2))) unsigned int u32x2;

__device__ __forceinline__ unsigned int f2bf(float f) {
    unsigned int u = __builtin_bit_cast(unsigned int, f);
    u += 0x7fffu + ((u >> 16) & 1u);          // RNE
    return u >> 16;
}
__device__ __forceinline__ float bf2f(unsigned int h) {
    unsigned int u = h << 16;
    return __builtin_bit_cast(float, u);
}

#define INV_E 0.36787944117144233f
#define RDEC  0.69220062755534635f            // exp(-1/e)

#define GLDS16(g, l) __builtin_amdgcn_global_load_lds(                         \
    (const __attribute__((address_space(1))) void*)(g),                        \
    (__attribute__((address_space(3))) void*)(l), 16, 0, 0)

// ---------------- kPre: W fp32 -> bf16 (once, 128 KB out) ----------------
__global__ __launch_bounds__(256)
void kPre(const float* __restrict__ Win, unsigned short* __restrict__ Wbf) {
    int i = ((int)blockIdx.x * 256 + (int)threadIdx.x) * 4;
    float4 v = *(const float4*)(Win + i);
    u32x2 p;
    p.x = f2bf(v.x) | (f2bf(v.y) << 16);
    p.y = f2bf(v.z) | (f2bf(v.w) << 16);
    *(u32x2*)(Wbf + i) = p;
}

// ---------------- kMain: fused conv-scan + proj GEMM, 1024 threads ----------
__global__ __launch_bounds__(1024)
void kMain(const float* __restrict__ x, const float* __restrict__ mask,
           const unsigned short* __restrict__ Wbf, const float* __restrict__ bin,
           float* __restrict__ out)
{
    __shared__ float          yF[BT][YFP];     // fwd partial F (fp32, 65.8 KB)
    __shared__ unsigned short yB[BT][YP];      // (B-v) then final y bf16 (33.8 KB)
    __shared__ unsigned short Wl[2][DD][32];   // W chunk dbuf (glds dest, 32 KB)
    __shared__ float wv[WIN], rp[WIN];
    __shared__ float cA[DD], cC[DD];           // scan carries (fwd@47, bwd@80)
    __shared__ float sp[16][BT];
    __shared__ float s_l[BT];

    const int tid  = threadIdx.x;
    const int orig = blockIdx.x;
    const int wg   = (orig & 7) * 32 + (orig >> 3);   // XCD-contiguous row tiles
    const int b    = wg >> 6;
    const int r0   = (wg & 63) * BT;
    const int base = r0 - HW;

    if (tid < WIN) {
        rp[tid] = __expf(-(float)tid * INV_E);
        int j = base + tid;
        wv[tid] = (j >= 0 && j < TT) ? __expf(mask[b * TT + j] * INV_E) : 0.0f;
    }
    __syncthreads();

    const int w = tid >> 6, lane = tid & 63;
    const int lr = lane & 15, lg = lane >> 4;
    const int wr = w >> 2, wc = w & 3;

    // W stage: one glds per thread per chunk (wave w covers rows 16w..16w+15)
    const int wlrow = 16 * w + (lane >> 2);
    const int wq    = (lane & 3) ^ (wlrow & 3);       // pre-swizzled source quarter
    auto wstage = [&](int ch, int buf) {
        const unsigned short* g = Wbf + (size_t)wlrow * DD + 32 * ch + 8 * wq;
        GLDS16(g, &Wl[buf][16 * w][0]);
    };
    wstage(0, 0);                                     // flies under the whole scan

    // ---- phase 1: 4 balanced depth-48 chains (g = tid>>8), column c ----
    // window rows t in [0,128), main rows t in [32,96), output i = t-32.
    {
        const int g = tid >> 8, c = tid & 255;
        const float* xc = x + (size_t)b * TT * DD + c;
        if (g == 0) {                                 // fwd [0,48): store i<16, carry cA@47
            float f = 0.0f;
            #pragma unroll 8
            for (int t = 0; t < 32; ++t) {
                int j = base + t; j = max(j, 0);
                f = fmaf(RDEC, f, xc[(size_t)j * DD] * wv[t]);
            }
            #pragma unroll 8
            for (int t = 32; t < 48; ++t) {
                f = fmaf(RDEC, f, xc[(size_t)(base + t) * DD] * wv[t]);
                yF[t - 32][c] = f;
            }
            cA[c] = f;
        } else if (g == 1) {                          // fwd [48,96): store i in [16,64)
            float f = 0.0f;
            #pragma unroll 8
            for (int t = 48; t < 96; ++t) {
                f = fmaf(RDEC, f, xc[(size_t)(base + t) * DD] * wv[t]);
                yF[t - 32][c] = f;
            }
        } else if (g == 2) {                          // bwd [80,128): store i>=48, carry cC@80
            float bb = 0.0f;
            #pragma unroll 8
            for (int t = 127; t >= 96; --t) {
                int j = base + t; j = min(j, TT - 1);
                bb = fmaf(RDEC, bb, xc[(size_t)j * DD] * wv[t]);
            }
            #pragma unroll 8
            for (int t = 95; t >= 80; --t) {
                float v = xc[(size_t)(base + t) * DD] * wv[t];
                bb = fmaf(RDEC, bb, v);
                yB[t - 32][c] = (unsigned short)f2bf(bb - v);
            }
            cC[c] = bb;
        } else {                                      // bwd [32,80): store i in [0,48)
            float bb = 0.0f;
            #pragma unroll 8
            for (int t = 79; t >= 32; --t) {
                float v = xc[(size_t)(base + t) * DD] * wv[t];
                bb = fmaf(RDEC, bb, v);
                yB[t - 32][c] = (unsigned short)f2bf(bb - v);
            }
        }
    }
    // attn row sums (bias term): 16 groups x 8 window terms
    {
        int row = tid & 63, q = tid >> 6;
        float s = 0.0f;
        #pragma unroll
        for (int tt = 0; tt < 8; ++tt) {
            int t = 8 * q + tt;
            int d = row + HW - t; d = (d < 0) ? -d : d;
            s = fmaf(rp[d], wv[t], s);
        }
        sp[q][row] = s;
    }
    __syncthreads();

    // ---- combine: y = F + (B-v) + [i>=16] rp[i-15]*cA + [i<48] rp[48-i]*cC ----
    #pragma unroll
    for (int e = 0; e < 16; ++e) {
        int idx = (e << 10) | tid;
        int i = idx >> 8, c = idx & 255;
        float yv = yF[i][c] + bf2f(yB[i][c]);
        if (i >= 16) yv += rp[i - 15] * cA[c];
        if (i < 48)  yv += rp[48 - i] * cC[c];
        yB[i][c] = (unsigned short)f2bf(yv);
    }
    if (tid < BT) {
        float s = 0.0f;
        #pragma unroll
        for (int q = 0; q < 16; ++q) s += sp[q][tid];
        s_l[tid] = s;
    }
    __syncthreads();                                  // yB final + Wl[0] ready

    // ---- phase 2: out = y @ W^T; 16 waves, 8 K-chunks, glds double-buffer ----
    f32x4 acc[4];
    #pragma unroll
    for (int n = 0; n < 4; ++n) acc[n] = (f32x4){0.f, 0.f, 0.f, 0.f};

    #pragma unroll
    for (int ch = 0; ch < 8; ++ch) {
        const int buf = ch & 1;
        if (ch < 7) wstage(ch + 1, buf ^ 1);
        short8 af = *(const short8*)&yB[16 * wr + lr][32 * ch + 8 * lg];
        #pragma unroll
        for (int n = 0; n < 4; ++n) {
            int rn = 64 * wc + 16 * n + lr;
            short8 bf8 = *(const short8*)&Wl[buf][rn][8 * (lg ^ (rn & 3))];
            acc[n] = __builtin_amdgcn_mfma_f32_16x16x32_bf16(af, bf8, acc[n], 0, 0, 0);
        }
        __syncthreads();                              // drains glds for next chunk
    }

    // ---- epilogue (C/D map: row=(lane>>4)*4+j, col=lane&15; validated) ----
    float bcol[4];
    #pragma unroll
    for (int n = 0; n < 4; ++n) bcol[n] = bin[64 * wc + 16 * n + lr];
    float* ob = out + ((size_t)(b * TT + r0)) * DD;
    #pragma unroll
    for (int n = 0; n < 4; ++n)
        #pragma unroll
        for (int j = 0; j < 4; ++j) {
            int i = 16 * wr + 4 * lg + j;
            ob[(size_t)i * DD + 64 * wc + 16 * n + lr] = acc[n][j] + s_l[i] * bcol[n];
        }
}

extern "C" void kernel_launch(void* const* d_in, const int* in_sizes, int n_in,
                              void* d_out, int out_size, void* d_ws, size_t ws_size,
                              hipStream_t stream) {
    const float* x    = (const float*)d_in[0];
    const float* mask = (const float*)d_in[1];
    const float* Win  = (const float*)d_in[2];
    const float* bin  = (const float*)d_in[3];
    float* out = (float*)d_out;

    const int nb = in_sizes[0] / (TT * DD);           // 4 batches
    unsigned short* Wbf = (unsigned short*)d_ws;      // 128 KB bf16 W

    hipLaunchKernelGGL(kPre, dim3(DD * DD / 1024), dim3(256), 0, stream, Win, Wbf);
    hipLaunchKernelGGL(kMain, dim3(nb * (TT / BT)), dim3(1024), 0, stream,
                       x, mask, Wbf, bin, out);
}